// Round 9
// baseline (567.212 us; speedup 1.0000x reference)
//
#include <hip/hip_runtime.h>

// GCN autoencoder: N=50000, E=800000, 128 -> 16 -> 128.
// Round 17: R16's cooperative mega never ran (absmax = |ref| on zeroed out,
// poison on re-poisoned run -> launch rejected; cooperative API + graph
// capture is unverifiable). Same fusion, graph-safe: plain launches + a
// homebrew grid barrier (device-scope atomics, 8 line-padded sub-counters,
// release-add/acquire-spin). Grid 512x256 = R14's native geometry so every
// phase body is the VERBATIM R14 kernel (160.6us proven):
//  p1: GEMM blocks 0..195 (thread-per-row, uniform LDS broadcasts)
//      + scatter blocks 196..511 (316 x 2536 edges, two-phase bucket scatter;
//      fewer blocks than R14's 500 -> 38% fewer gcur atomics, 5-edge runs).
//  p2: counting sort -> CSR, dinv, h1*=dinv (bucket = bid).
//  p3: encoder agg = R14 k3 as 2 virtual 64-node passes.
//  p4: decoder agg + W2 epilogue = R14 k4's 128-node block as 2 passes.
// Init kernel zeroes gcur + barrier counters (replaces memset dispatch).
// Residency: 16.9KB LDS / 4 waves / VGPR<=128 -> >=4 blocks/CU capacity,
// 2x margin over 512 blocks; no cooperative API needed.

#define N_NODES 50000
#define N_EDGES 800000
#define D_IN    128
#define D_H     16
#define K_BUCK  512
#define NPB2    98       // bucket = dst / 98 (max 49999/98 = 510)
#define BSHIFT  11
#define BCAP    (1 << BSHIFT)
#define GC_PAD  16
#define GRID    512
#define NTHR    256
#define GEMM_BLKS 196    // 196*256 = 50176 >= 50000 rows
#define SC_BLKS 316
#define SC_CH   2536     // 316*2536 = 801376 >= 800000
#define SC_I4   634      // 2536/4 int4 items per scatter block
#define NBLK3   782      // ceil(50000/64)
#define NBLK4   391      // ceil(50000/128)
#define BAR_PAD 16       // ints: 64B line padding per sub-counter
#define NBAR    3

union SMem {
    float w1s[D_IN * D_H];                                  // p1 GEMM (8 KB)
    struct { int hist[K_BUCK]; int cur[K_BUCK]; } s;        // p1 scatter (4 KB)
    struct { int cnt[NPB2]; int pref[NPB2]; int cur[NPB2]; float sdi[NPB2]; } p2;
    struct { float agL[128 * 17]; float w2s[D_H * D_IN]; } p4;   // 16.9 KB
};

__global__ __launch_bounds__(256) void k_init(int* __restrict__ gcur,
                                              int* __restrict__ bc) {
    int t = blockIdx.x * 256 + threadIdx.x;
    if (t < K_BUCK * GC_PAD) gcur[t] = 0;
    if (t < NBAR * 8 * BAR_PAD) bc[t] = 0;
}

__device__ __forceinline__ void gbar(int* bc, int phase) {
    __syncthreads();
    if (threadIdx.x == 0) {
        int* base = bc + phase * 8 * BAR_PAD;
        __threadfence();   // release my phase's writes (device scope)
        __hip_atomic_fetch_add(base + (blockIdx.x & 7) * BAR_PAD, 1,
                               __ATOMIC_RELEASE, __HIP_MEMORY_SCOPE_AGENT);
        int s;
        do {
            s = 0;
            #pragma unroll
            for (int j = 0; j < 8; ++j)
                s += __hip_atomic_load(base + j * BAR_PAD,
                                       __ATOMIC_ACQUIRE, __HIP_MEMORY_SCOPE_AGENT);
            if (s < GRID) __builtin_amdgcn_s_sleep(2);
        } while (s < GRID);
    }
    __syncthreads();
}

#define PACKH(pk, d) { \
    int c0 = d.x / NPB2, c1 = d.y / NPB2, c2 = d.z / NPB2, c3 = d.w / NPB2; \
    pk.x = (c0 << 7) | (d.x - c0 * NPB2); pk.y = (c1 << 7) | (d.y - c1 * NPB2); \
    pk.z = (c2 << 7) | (d.z - c2 * NPB2); pk.w = (c3 << 7) | (d.w - c3 * NPB2); \
    atomicAdd(&sm.s.hist[c0], 1); atomicAdd(&sm.s.hist[c1], 1); \
    atomicAdd(&sm.s.hist[c2], 1); atomicAdd(&sm.s.hist[c3], 1); }

#define SCAT(pk, sv) { \
    int c0 = pk.x >> 7, c1 = pk.y >> 7, c2 = pk.z >> 7, c3 = pk.w >> 7; \
    int q0 = atomicAdd(&sm.s.cur[c0], 1); int q1 = atomicAdd(&sm.s.cur[c1], 1); \
    int q2 = atomicAdd(&sm.s.cur[c2], 1); int q3 = atomicAdd(&sm.s.cur[c3], 1); \
    if (q0 < ((c0 + 1) << BSHIFT)) arr[q0] = (sv.x << 7) | (pk.x & 127); \
    if (q1 < ((c1 + 1) << BSHIFT)) arr[q1] = (sv.y << 7) | (pk.y & 127); \
    if (q2 < ((c2 + 1) << BSHIFT)) arr[q2] = (sv.z << 7) | (pk.z & 127); \
    if (q3 < ((c3 + 1) << BSHIFT)) arr[q3] = (sv.w << 7) | (pk.w & 127); }

__global__ __launch_bounds__(NTHR) void mega(
        const int* __restrict__ src, const int* __restrict__ dst,
        const float* __restrict__ x, const float* __restrict__ W1,
        const float* __restrict__ b1, const float* __restrict__ W2,
        const float* __restrict__ b2,
        int* __restrict__ gcur, int* __restrict__ bc, float* __restrict__ dinv,
        float* __restrict__ h1, float* __restrict__ zs,
        int2* __restrict__ meta, int* __restrict__ arr,
        int* __restrict__ csr, float* __restrict__ out) {
    __shared__ __align__(16) SMem sm;
    int bid = blockIdx.x, tid = threadIdx.x;

    // ---- phase 1: [GEMM 0..195] + [bucket scatter 196..511] ----
    if (bid < GEMM_BLKS) {
        for (int i = tid; i < D_IN * D_H; i += NTHR) sm.w1s[i] = W1[i];
        __syncthreads();
        int row = bid * NTHR + tid;
        if (row < N_NODES) {
            const float4* xr = (const float4*)(x + row * D_IN);
            const float4* w4 = (const float4*)sm.w1s;
            float4 a0 = {0, 0, 0, 0}, a1 = a0, a2 = a0, a3 = a0;
            for (int k4 = 0; k4 < D_IN / 4; ++k4) {
                float4 xv = xr[k4];
                #pragma unroll
                for (int j = 0; j < 4; ++j) {
                    float xk = (j == 0) ? xv.x : (j == 1) ? xv.y : (j == 2) ? xv.z : xv.w;
                    const float4* wr = w4 + (k4 * 4 + j) * 4;   // wave-uniform
                    float4 w0 = wr[0], w1v = wr[1], w2v = wr[2], w3v = wr[3];
                    a0.x += xk * w0.x;  a0.y += xk * w0.y;  a0.z += xk * w0.z;  a0.w += xk * w0.w;
                    a1.x += xk * w1v.x; a1.y += xk * w1v.y; a1.z += xk * w1v.z; a1.w += xk * w1v.w;
                    a2.x += xk * w2v.x; a2.y += xk * w2v.y; a2.z += xk * w2v.z; a2.w += xk * w2v.w;
                    a3.x += xk * w3v.x; a3.y += xk * w3v.y; a3.z += xk * w3v.z; a3.w += xk * w3v.w;
                }
            }
            float4* hr = (float4*)(h1 + row * D_H);
            hr[0] = a0; hr[1] = a1; hr[2] = a2; hr[3] = a3;
        }
    } else {
        int base_e = (bid - GEMM_BLKS) * SC_CH;
        int ni4 = min((N_EDGES - base_e) >> 2, SC_I4);
        for (int b = tid; b < K_BUCK; b += NTHR) sm.s.hist[b] = 0;
        __syncthreads();
        const int4* d4p = (const int4*)(dst + base_e);
        const int4* s4p = (const int4*)(src + base_e);
        int4 pk0, pk1, pk2;
        bool a0 = tid < ni4, a1 = tid + 256 < ni4, a2 = tid + 512 < ni4;
        if (a0) { int4 d = d4p[tid];       PACKH(pk0, d); }
        if (a1) { int4 d = d4p[tid + 256]; PACKH(pk1, d); }
        if (a2) { int4 d = d4p[tid + 512]; PACKH(pk2, d); }
        __syncthreads();
        for (int b = tid; b < K_BUCK; b += NTHR)
            sm.s.cur[b] = (b << BSHIFT) + atomicAdd(&gcur[b * GC_PAD], sm.s.hist[b]);
        __syncthreads();
        if (a0) { int4 sv = s4p[tid];       SCAT(pk0, sv); }
        if (a1) { int4 sv = s4p[tid + 256]; SCAT(pk1, sv); }
        if (a2) { int4 sv = s4p[tid + 512]; SCAT(pk2, sv); }
    }
    gbar(bc, 0);

    // ---- phase 2: counting sort -> CSR; dinv; h1 *= dinv (bucket = bid) ----
    {
        int k = bid;
        for (int i = tid; i < NPB2; i += NTHR) sm.p2.cnt[i] = 0;
        __syncthreads();
        int count = min(gcur[k * GC_PAD], BCAP);
        int base = k << BSHIFT;
        for (int i = tid; i < count; i += NTHR) atomicAdd(&sm.p2.cnt[arr[base + i] & 127], 1);
        __syncthreads();
        if (tid == 0) {
            int run = 0;
            for (int l = 0; l < NPB2; ++l) { sm.p2.pref[l] = run; run += sm.p2.cnt[l]; }
        }
        __syncthreads();
        int n0 = k * NPB2;
        int ncnt = min(NPB2, N_NODES - n0);   // <=0 for bucket 511
        for (int l = tid; l < ncnt; l += NTHR) {
            sm.p2.cur[l] = sm.p2.pref[l];
            meta[n0 + l] = make_int2(base + sm.p2.pref[l], sm.p2.cnt[l]);
            float di = rsqrtf((float)sm.p2.cnt[l] + 1.0f);   // +1 = self loop
            sm.p2.sdi[l] = di;
            dinv[n0 + l] = di;
        }
        __syncthreads();
        for (int g = tid; g < ncnt * 4; g += NTHR) {
            int l = g >> 2;
            float di = sm.p2.sdi[l];
            float4* p = (float4*)(h1 + (n0 + l) * D_H);
            float4 v = p[g & 3];
            v.x *= di; v.y *= di; v.z *= di; v.w *= di;
            p[g & 3] = v;
        }
        for (int i = tid; i < count; i += NTHR) {
            int p = arr[base + i];
            int l = p & 127;
            int pos = atomicAdd(&sm.p2.cur[l], 1);
            csr[base + pos] = p >> 7;
        }
    }
    gbar(bc, 1);

    // ---- phase 3: encoder agg (R14 k3, 2 virtual 64-node passes) ----
    {
        const float4* h1s4 = (const float4*)h1;
        float4* zs4 = (float4*)zs;
        int q = tid & 3, qb = tid & 60;
        #pragma unroll
        for (int pass = 0; pass < 2; ++pass) {
            int vb = bid + pass * GRID;
            int n = vb * 64 + (tid >> 2);
            if (vb < NBLK3 && n < N_NODES) {
                int2 m = meta[n];
                int e = m.x, end = m.x + m.y;
                float4 acc = {0.0f, 0.0f, 0.0f, 0.0f};
                for (; e < end; e += 4) {
                    int myidx = 0;
                    if (e + q < end) myidx = csr[e + q];
                    #pragma unroll
                    for (int j = 0; j < 4; ++j) {
                        int idx = __shfl(myidx, qb + j, 64);
                        if (e + j < end) {
                            float4 v = h1s4[idx * 4 + q];
                            acc.x += v.x; acc.y += v.y; acc.z += v.z; acc.w += v.w;
                        }
                    }
                }
                float di = dinv[n];
                float4 hv = h1s4[n * 4 + q];
                float4 bv = ((const float4*)b1)[q];
                float4 z;
                z.x = di * (di * (acc.x + hv.x) + bv.x);
                z.y = di * (di * (acc.y + hv.y) + bv.y);
                z.z = di * (di * (acc.z + hv.z) + bv.z);
                z.w = di * (di * (acc.w + hv.w) + bv.w);
                zs4[n * 4 + q] = z;
            }
        }
    }
    gbar(bc, 2);

    // ---- phase 4: decoder agg + W2 epilogue (R14 k4 as 2 passes) ----
    {
        const float4* zs4 = (const float4*)zs;
        for (int i = tid; i < D_H * D_IN; i += NTHR) sm.p4.w2s[i] = W2[i];
        int q = tid & 3, qb = tid & 60;
        bool blkact = (bid < NBLK4);
        int n0b = bid * 128;
        if (blkact) {
            #pragma unroll
            for (int pass = 0; pass < 2; ++pass) {
                int nloc = pass * 64 + (tid >> 2);
                int n = n0b + nloc;
                if (n < N_NODES) {
                    int2 m = meta[n];
                    int e = m.x, end = m.x + m.y;
                    float4 acc = {0.0f, 0.0f, 0.0f, 0.0f};
                    for (; e < end; e += 4) {
                        int myidx = 0;
                        if (e + q < end) myidx = csr[e + q];
                        #pragma unroll
                        for (int j = 0; j < 4; ++j) {
                            int idx = __shfl(myidx, qb + j, 64);
                            if (e + j < end) {
                                float4 v = zs4[idx * 4 + q];
                                acc.x += v.x; acc.y += v.y; acc.z += v.z; acc.w += v.w;
                            }
                        }
                    }
                    float di = dinv[n];
                    float4 zv = zs4[n * 4 + q];
                    sm.p4.agL[nloc * 17 + q * 4 + 0] = di * (acc.x + zv.x);
                    sm.p4.agL[nloc * 17 + q * 4 + 1] = di * (acc.y + zv.y);
                    sm.p4.agL[nloc * 17 + q * 4 + 2] = di * (acc.z + zv.z);
                    sm.p4.agL[nloc * 17 + q * 4 + 3] = di * (acc.w + zv.w);
                }
            }
        }
        __syncthreads();
        if (blkact) {
            #pragma unroll
            for (int pass = 0; pass < 2; ++pass) {
                int quarter = pass * 2 + (tid >> 7);   // wave-uniform
                int ne = tid & 127;
                if (n0b + ne < N_NODES) {
                    const float* arow = &sm.p4.agL[ne * 17];
                    float4 o[8];
                    const float4* b2q = (const float4*)(b2 + quarter * 32);
                    #pragma unroll
                    for (int u = 0; u < 8; ++u) o[u] = b2q[u];
                    #pragma unroll
                    for (int c = 0; c < D_H; ++c) {
                        float ac = arow[c];
                        const float4* wr = (const float4*)(sm.p4.w2s + c * D_IN + quarter * 32);
                        #pragma unroll
                        for (int u = 0; u < 8; ++u) {
                            float4 w = wr[u];
                            o[u].x += ac * w.x; o[u].y += ac * w.y;
                            o[u].z += ac * w.z; o[u].w += ac * w.w;
                        }
                    }
                    float4* orow = (float4*)(out + (n0b + ne) * D_IN + quarter * 32);
                    #pragma unroll
                    for (int u = 0; u < 8; ++u) orow[u] = o[u];
                }
            }
        }
    }
}

extern "C" void kernel_launch(void* const* d_in, const int* in_sizes, int n_in,
                              void* d_out, int out_size, void* d_ws, size_t ws_size,
                              hipStream_t stream) {
    const float* x  = (const float*)d_in[0];
    const int*   ei = (const int*)d_in[1];   // [2, E]: src then dst
    const float* W1 = (const float*)d_in[2];
    const float* b1 = (const float*)d_in[3];
    const float* W2 = (const float*)d_in[4];
    const float* b2 = (const float*)d_in[5];
    float* out = (float*)d_out;

    const int* src = ei;
    const int* dst = ei + N_EDGES;

    // ws carve: gcur | bc (barrier ctrs) | dinv[N] | h1[N*16] | zs[N*16]
    //           | meta[N int2] | arr[512*2048] | csr[512*2048]   (~15.2 MB)
    char* base = (char*)d_ws;
    int*    gcur = (int*)base;                 base += K_BUCK * GC_PAD * 4;
    int*    bc   = (int*)base;                 base += NBAR * 8 * BAR_PAD * 4;
    float*  dinv = (float*)base;               base += N_NODES * 4;
    float*  h1   = (float*)base;               base += N_NODES * D_H * 4;
    float*  zs   = (float*)base;               base += N_NODES * D_H * 4;
    int2*   meta = (int2*)base;                base += N_NODES * 8;
    int*    arr  = (int*)base;                 base += K_BUCK * BCAP * 4;
    int*    csr  = (int*)base;                 base += K_BUCK * BCAP * 4;

    k_init<<<(K_BUCK * GC_PAD + 255) / 256, 256, 0, stream>>>(gcur, bc);
    mega<<<GRID, NTHR, 0, stream>>>(src, dst, x, W1, b1, W2, b2,
                                    gcur, bc, dinv, h1, zs, meta, arr, csr, out);
}

// Round 10
// 157.565 us; speedup vs baseline: 3.5999x; 3.5999x over previous
//
#include <hip/hip_runtime.h>

// GCN autoencoder: N=50000, E=800000, 128 -> 16 -> 128.
// Round 18: REVERT to R14 (proven best, 160.6us) after both fusion paths
// failed: cooperative launch rejected by harness (R16); homebrew grid
// barrier forced per-barrier cross-XCD L2 flushes (R17: 534us kernel,
// FETCH/WRITE inflated 47/70MB, 96% of time spent waiting). Kernel-launch
// boundaries ARE the cheap grid barrier on MI355X.
// One carry-over from R17's (correct) phase 1: scatter geometry 316 blocks
// x 2536 edges, 3 reg-cached int4 packs/thread -> 38% fewer gcur
// reservation atomics than R14's 500 blocks, longer per-bucket runs
// (mean 5 edges) for write merging. k2/k3/k4 verbatim R14.

#define N_NODES 50000
#define N_EDGES 800000
#define D_IN    128
#define D_H     16
#define K_BUCK  512
#define NPB2    98       // bucket = dst / 98 (max 49999/98 = 510)
#define BSHIFT  11
#define BCAP    (1 << BSHIFT)   // 2048 csr slots per bucket; mean 1562, sd 40
#define GC_PAD  16       // gcur stride in ints (64 B line padding)
#define G_BLKS  196      // ceil(50000/256) GEMM blocks (thread-per-row)
#define SC_BLKS 316
#define SC_CH   2536     // 316*2536 = 801376 >= 800000
#define SC_I4   634      // int4 items per scatter block
#define K4_NPB  128      // nodes per k4 block (512 threads)

#define PACKH(pk, d) { \
    int c0 = d.x / NPB2, c1 = d.y / NPB2, c2 = d.z / NPB2, c3 = d.w / NPB2; \
    pk.x = (c0 << 7) | (d.x - c0 * NPB2); pk.y = (c1 << 7) | (d.y - c1 * NPB2); \
    pk.z = (c2 << 7) | (d.z - c2 * NPB2); pk.w = (c3 << 7) | (d.w - c3 * NPB2); \
    atomicAdd(&hist[c0], 1); atomicAdd(&hist[c1], 1); \
    atomicAdd(&hist[c2], 1); atomicAdd(&hist[c3], 1); }

#define SCAT(pk, sv) { \
    int c0 = pk.x >> 7, c1 = pk.y >> 7, c2 = pk.z >> 7, c3 = pk.w >> 7; \
    int q0 = atomicAdd(&cur[c0], 1); int q1 = atomicAdd(&cur[c1], 1); \
    int q2 = atomicAdd(&cur[c2], 1); int q3 = atomicAdd(&cur[c3], 1); \
    if (q0 < ((c0 + 1) << BSHIFT)) arr[q0] = (sv.x << 7) | (pk.x & 127); \
    if (q1 < ((c1 + 1) << BSHIFT)) arr[q1] = (sv.y << 7) | (pk.y & 127); \
    if (q2 < ((c2 + 1) << BSHIFT)) arr[q2] = (sv.z << 7) | (pk.z & 127); \
    if (q3 < ((c3 + 1) << BSHIFT)) arr[q3] = (sv.w << 7) | (pk.w & 127); }

// ---- K1: fused [h1 GEMM (blocks 0..195)] + [bucket scatter (196..511)] ----
__global__ __launch_bounds__(256) void k1_fused(
        const int* __restrict__ src, const int* __restrict__ dst,
        const float* __restrict__ x, const float* __restrict__ W1,
        int* __restrict__ gcur, float* __restrict__ h1, int* __restrict__ arr) {
    __shared__ __align__(16) float w1s[D_IN * D_H];   // GEMM segment (8 KB)
    __shared__ int hist[K_BUCK];        // scatter segment (2+2 KB)
    __shared__ int cur[K_BUCK];
    int bid = blockIdx.x;
    int tid = threadIdx.x;

    if (bid < G_BLKS) {
        // ---- h1 = x @ W1: thread-per-row, wave-uniform W1 broadcasts ----
        for (int i = tid; i < D_IN * D_H; i += 256) w1s[i] = W1[i];
        __syncthreads();
        int row = bid * 256 + tid;
        if (row >= N_NODES) return;
        const float4* xr = (const float4*)(x + row * D_IN);
        const float4* w4 = (const float4*)w1s;
        float4 a0 = {0, 0, 0, 0}, a1 = a0, a2 = a0, a3 = a0;
        for (int k4 = 0; k4 < D_IN / 4; ++k4) {
            float4 xv = xr[k4];
            #pragma unroll
            for (int j = 0; j < 4; ++j) {
                float xk = (j == 0) ? xv.x : (j == 1) ? xv.y : (j == 2) ? xv.z : xv.w;
                const float4* wr = w4 + (k4 * 4 + j) * 4;   // uniform across wave
                float4 w0 = wr[0], w1v = wr[1], w2v = wr[2], w3v = wr[3];
                a0.x += xk * w0.x;  a0.y += xk * w0.y;  a0.z += xk * w0.z;  a0.w += xk * w0.w;
                a1.x += xk * w1v.x; a1.y += xk * w1v.y; a1.z += xk * w1v.z; a1.w += xk * w1v.w;
                a2.x += xk * w2v.x; a2.y += xk * w2v.y; a2.z += xk * w2v.z; a2.w += xk * w2v.w;
                a3.x += xk * w3v.x; a3.y += xk * w3v.y; a3.z += xk * w3v.z; a3.w += xk * w3v.w;
            }
        }
        float4* hr = (float4*)(h1 + row * D_H);
        hr[0] = a0; hr[1] = a1; hr[2] = a2; hr[3] = a3;
    } else {
        // ---- two-phase bucket scatter, dst read once (reg-cached packs) ----
        int base_e = (bid - G_BLKS) * SC_CH;
        int ni4 = min((N_EDGES - base_e) >> 2, SC_I4);
        for (int b = tid; b < K_BUCK; b += 256) hist[b] = 0;
        __syncthreads();
        const int4* d4p = (const int4*)(dst + base_e);
        const int4* s4p = (const int4*)(src + base_e);
        int4 pk0, pk1, pk2;
        bool a0 = tid < ni4, a1 = tid + 256 < ni4, a2 = tid + 512 < ni4;
        if (a0) { int4 d = d4p[tid];       PACKH(pk0, d); }
        if (a1) { int4 d = d4p[tid + 256]; PACKH(pk1, d); }
        if (a2) { int4 d = d4p[tid + 512]; PACKH(pk2, d); }
        __syncthreads();
        for (int b = tid; b < K_BUCK; b += 256)
            cur[b] = (b << BSHIFT) + atomicAdd(&gcur[b * GC_PAD], hist[b]);
        __syncthreads();
        if (a0) { int4 sv = s4p[tid];       SCAT(pk0, sv); }
        if (a1) { int4 sv = s4p[tid + 256]; SCAT(pk1, sv); }
        if (a2) { int4 sv = s4p[tid + 512]; SCAT(pk2, sv); }
    }
}

// ---- K2: per-bucket counting sort -> CSR; dinv; scale h1 *= dinv in place ----
__global__ __launch_bounds__(256) void k2_build_csr(
        const int* __restrict__ arr, const int* __restrict__ gcur,
        float* __restrict__ h1, float* __restrict__ dinv,
        int* __restrict__ csr, int2* __restrict__ meta) {
    __shared__ int cnt[NPB2];
    __shared__ int pref[NPB2];
    __shared__ int cur[NPB2];
    __shared__ float sdi[NPB2];
    int k = blockIdx.x, tid = threadIdx.x;
    for (int i = tid; i < NPB2; i += 256) cnt[i] = 0;
    __syncthreads();
    int count = min(gcur[k * GC_PAD], BCAP);
    int base = k << BSHIFT;
    for (int i = tid; i < count; i += 256) atomicAdd(&cnt[arr[base + i] & 127], 1);
    __syncthreads();
    if (tid == 0) {
        int run = 0;
        for (int l = 0; l < NPB2; ++l) { pref[l] = run; run += cnt[l]; }
    }
    __syncthreads();
    int n0 = k * NPB2;
    int ncnt = min(NPB2, N_NODES - n0);
    for (int l = tid; l < ncnt; l += 256) {
        cur[l] = pref[l];
        meta[n0 + l] = make_int2(base + pref[l], cnt[l]);
        float di = rsqrtf((float)cnt[l] + 1.0f);   // +1 = self loop
        sdi[l] = di;
        dinv[n0 + l] = di;
    }
    __syncthreads();
    // scale h1 in place: h1s[n][:] = h1[n][:] * dinv[n]
    for (int g = tid; g < ncnt * 4; g += 256) {
        int l = g >> 2;
        float di = sdi[l];
        float4* p = (float4*)(h1 + (n0 + l) * D_H);
        float4 v = p[g & 3];
        v.x *= di; v.y *= di; v.z *= di; v.w *= di;
        p[g & 3] = v;
    }
    // scatter to csr (grouped by local dst)
    for (int i = tid; i < count; i += 256) {
        int p = arr[base + i];
        int l = p & 127;
        int pos = atomicAdd(&cur[l], 1);
        csr[base + pos] = p >> 7;
    }
}

// ---- K3: encoder agg, 4 lanes/node, register accumulate.
//      zs[n][:] = di*( di*(h1s_self + S h1s[src]) + b1 )   (pre-scaled z) ----
__global__ __launch_bounds__(256) void k3_agg_enc(
        const float4* __restrict__ h1s4, const int* __restrict__ csr,
        const int2* __restrict__ meta, const float* __restrict__ dinv,
        const float* __restrict__ b1, float4* __restrict__ zs4) {
    int tid = threadIdx.x;
    int q = tid & 3;
    int n = blockIdx.x * 64 + (tid >> 2);
    if (n >= N_NODES) return;
    int qb = tid & 60;                 // quad base lane within wave
    int2 m = meta[n];                  // same addr across quad -> broadcast
    int e = m.x, end = m.x + m.y;
    float4 acc = {0.0f, 0.0f, 0.0f, 0.0f};
    for (; e < end; e += 4) {
        int myidx = 0;
        if (e + q < end) myidx = csr[e + q];   // coalesced 16B per quad
        #pragma unroll
        for (int j = 0; j < 4; ++j) {
            int idx = __shfl(myidx, qb + j, 64);
            if (e + j < end) {
                float4 v = h1s4[idx * 4 + q];  // quad covers one 64B line
                acc.x += v.x; acc.y += v.y; acc.z += v.z; acc.w += v.w;
            }
        }
    }
    float di = dinv[n];
    float4 hv = h1s4[n * 4 + q];       // self (already *dinv)
    float4 bv = ((const float4*)b1)[q];
    float4 z;
    z.x = di * (di * (acc.x + hv.x) + bv.x);
    z.y = di * (di * (acc.y + hv.y) + bv.y);
    z.z = di * (di * (acc.z + hv.z) + bv.z);
    z.w = di * (di * (acc.w + hv.w) + bv.w);
    zs4[n * 4 + q] = z;
}

// ---- K4: decoder agg (CSR quad) + W2 GEMM epilogue with uniform broadcasts ----
__global__ __launch_bounds__(512) void k4_agg_dec_out(
        const float4* __restrict__ zs4, const int* __restrict__ csr,
        const int2* __restrict__ meta, const float* __restrict__ dinv,
        const float* __restrict__ W2, const float* __restrict__ b2,
        float* __restrict__ out) {
    __shared__ float agL[K4_NPB * 17];                // 8.7 KB (pad 17: bank-clean)
    __shared__ __align__(16) float w2s[D_H * D_IN];   // 8 KB
    int tid = threadIdx.x;
    for (int i = tid; i < D_H * D_IN; i += 512) w2s[i] = W2[i];
    int q = tid & 3;
    int nloc = tid >> 2;               // 0..127
    int n0 = blockIdx.x * K4_NPB;
    int n = n0 + nloc;
    int qb = tid & 60;
    if (n < N_NODES) {
        int2 m = meta[n];
        int e = m.x, end = m.x + m.y;
        float4 acc = {0.0f, 0.0f, 0.0f, 0.0f};
        for (; e < end; e += 4) {
            int myidx = 0;
            if (e + q < end) myidx = csr[e + q];
            #pragma unroll
            for (int j = 0; j < 4; ++j) {
                int idx = __shfl(myidx, qb + j, 64);
                if (e + j < end) {
                    float4 v = zs4[idx * 4 + q];
                    acc.x += v.x; acc.y += v.y; acc.z += v.z; acc.w += v.w;
                }
            }
        }
        float di = dinv[n];
        float4 zv = zs4[n * 4 + q];    // self (zs pre-scaled)
        agL[nloc * 17 + q * 4 + 0] = di * (acc.x + zv.x);
        agL[nloc * 17 + q * 4 + 1] = di * (acc.y + zv.y);
        agL[nloc * 17 + q * 4 + 2] = di * (acc.z + zv.z);
        agL[nloc * 17 + q * 4 + 3] = di * (acc.w + zv.w);
    }
    __syncthreads();
    // epilogue: thread = (quarter = tid>>7 [wave-aligned], ne = tid&127)
    // w2s reads are same-address broadcasts across the wave (quarter uniform).
    int quarter = tid >> 7;
    int ne = tid & 127;
    if (n0 + ne < N_NODES) {
        const float* arow = &agL[ne * 17];
        float4 o[8];
        const float4* b2q = (const float4*)(b2 + quarter * 32);
        #pragma unroll
        for (int u = 0; u < 8; ++u) o[u] = b2q[u];
        #pragma unroll
        for (int c = 0; c < D_H; ++c) {
            float ac = arow[c];
            const float4* wr = (const float4*)(w2s + c * D_IN + quarter * 32);
            #pragma unroll
            for (int u = 0; u < 8; ++u) {
                float4 w = wr[u];
                o[u].x += ac * w.x; o[u].y += ac * w.y;
                o[u].z += ac * w.z; o[u].w += ac * w.w;
            }
        }
        float4* orow = (float4*)(out + (n0 + ne) * D_IN + quarter * 32);
        #pragma unroll
        for (int u = 0; u < 8; ++u) orow[u] = o[u];
    }
}

extern "C" void kernel_launch(void* const* d_in, const int* in_sizes, int n_in,
                              void* d_out, int out_size, void* d_ws, size_t ws_size,
                              hipStream_t stream) {
    const float* x  = (const float*)d_in[0];
    const int*   ei = (const int*)d_in[1];   // [2, E]: src then dst
    const float* W1 = (const float*)d_in[2];
    const float* b1 = (const float*)d_in[3];
    const float* W2 = (const float*)d_in[4];
    const float* b2 = (const float*)d_in[5];
    float* out = (float*)d_out;

    const int* src = ei;
    const int* dst = ei + N_EDGES;

    // ws carve: gcur | dinv[N] | h1[N*16] | zs[N*16] | meta[N int2]
    //           | arr[512*2048] | csr[512*2048]   (~15.2 MB)
    char* base = (char*)d_ws;
    int*    gcur = (int*)base;                 base += K_BUCK * GC_PAD * 4;
    float*  dinv = (float*)base;               base += N_NODES * 4;
    float*  h1   = (float*)base;               base += N_NODES * D_H * 4;
    float*  zs   = (float*)base;               base += N_NODES * D_H * 4;
    int2*   meta = (int2*)base;                base += N_NODES * 8;
    int*    arr  = (int*)base;                 base += K_BUCK * BCAP * 4;
    int*    csr  = (int*)base;                 base += K_BUCK * BCAP * 4;

    hipMemsetAsync(gcur, 0, K_BUCK * GC_PAD * sizeof(int), stream);

    k1_fused<<<G_BLKS + SC_BLKS, 256, 0, stream>>>(src, dst, x, W1, gcur, h1, arr);
    k2_build_csr<<<K_BUCK, 256, 0, stream>>>(arr, gcur, h1, dinv, csr, meta);
    k3_agg_enc<<<(N_NODES + 63) / 64, 256, 0, stream>>>((const float4*)h1, csr, meta, dinv, b1, (float4*)zs);
    k4_agg_dec_out<<<(N_NODES + K4_NPB - 1) / K4_NPB, 512, 0, stream>>>((const float4*)zs, csr, meta, dinv, W2, b2, out);
}

// Round 11
// 149.515 us; speedup vs baseline: 3.7937x; 1.0538x over previous
//
#include <hip/hip_runtime.h>

// GCN autoencoder: N=50000, E=800000, 128 -> 16 -> 128.
// Round 19: halve the bucket count (512 -> 256) to double scatter run
// length. R18 analysis: k1's scatter (~24us of its ~30) is bound by arr
// write-back granularity -- runs of 5 packed ints (20B) dirty a full 64B
// line each (316x512 lines). K_BUCK=256 -> runs of ~10 (40B), line-touches
// and gcur reservation atomics both halve. BCAP 4096 (mean 3136, 17 sigma).
// k2 restructured for 256 blocks: 512 threads + single-arr-read LDS staging
// (bucket entries <=16KB staged once; hist AND scatter served from LDS,
// deleting the 3.2MB global re-read). k3/k4 verbatim (meta is absolute).
// Pack format now (src<<8)|dl, dl<196.

#define N_NODES 50000
#define N_EDGES 800000
#define D_IN    128
#define D_H     16
#define K_BUCK  256
#define NPB2    196      // bucket = dst / 196 (max 49999/196 = 255)
#define BSHIFT  12
#define BCAP    (1 << BSHIFT)   // 4096 slots; mean 3136, sd 56 -> 17 sigma
#define GC_PAD  16       // gcur stride in ints (64 B line padding)
#define G_BLKS  196      // ceil(50000/256) GEMM blocks (thread-per-row)
#define SC_BLKS 316
#define SC_CH   2536     // 316*2536 = 801376 >= 800000
#define SC_I4   634      // int4 items per scatter block
#define K4_NPB  128      // nodes per k4 block (512 threads)

#define PACKH(pk, d) { \
    int c0 = d.x / NPB2, c1 = d.y / NPB2, c2 = d.z / NPB2, c3 = d.w / NPB2; \
    pk.x = (c0 << 8) | (d.x - c0 * NPB2); pk.y = (c1 << 8) | (d.y - c1 * NPB2); \
    pk.z = (c2 << 8) | (d.z - c2 * NPB2); pk.w = (c3 << 8) | (d.w - c3 * NPB2); \
    atomicAdd(&hist[c0], 1); atomicAdd(&hist[c1], 1); \
    atomicAdd(&hist[c2], 1); atomicAdd(&hist[c3], 1); }

#define SCAT(pk, sv) { \
    int c0 = pk.x >> 8, c1 = pk.y >> 8, c2 = pk.z >> 8, c3 = pk.w >> 8; \
    int q0 = atomicAdd(&cur[c0], 1); int q1 = atomicAdd(&cur[c1], 1); \
    int q2 = atomicAdd(&cur[c2], 1); int q3 = atomicAdd(&cur[c3], 1); \
    if (q0 < ((c0 + 1) << BSHIFT)) arr[q0] = (sv.x << 8) | (pk.x & 255); \
    if (q1 < ((c1 + 1) << BSHIFT)) arr[q1] = (sv.y << 8) | (pk.y & 255); \
    if (q2 < ((c2 + 1) << BSHIFT)) arr[q2] = (sv.z << 8) | (pk.z & 255); \
    if (q3 < ((c3 + 1) << BSHIFT)) arr[q3] = (sv.w << 8) | (pk.w & 255); }

// ---- K1: fused [h1 GEMM (blocks 0..195)] + [bucket scatter (196..511)] ----
__global__ __launch_bounds__(256) void k1_fused(
        const int* __restrict__ src, const int* __restrict__ dst,
        const float* __restrict__ x, const float* __restrict__ W1,
        int* __restrict__ gcur, float* __restrict__ h1, int* __restrict__ arr) {
    __shared__ __align__(16) float w1s[D_IN * D_H];   // GEMM segment (8 KB)
    __shared__ int hist[K_BUCK];        // scatter segment (1+1 KB)
    __shared__ int cur[K_BUCK];
    int bid = blockIdx.x;
    int tid = threadIdx.x;

    if (bid < G_BLKS) {
        // ---- h1 = x @ W1: thread-per-row, wave-uniform W1 broadcasts ----
        for (int i = tid; i < D_IN * D_H; i += 256) w1s[i] = W1[i];
        __syncthreads();
        int row = bid * 256 + tid;
        if (row >= N_NODES) return;
        const float4* xr = (const float4*)(x + row * D_IN);
        const float4* w4 = (const float4*)w1s;
        float4 a0 = {0, 0, 0, 0}, a1 = a0, a2 = a0, a3 = a0;
        for (int k4 = 0; k4 < D_IN / 4; ++k4) {
            float4 xv = xr[k4];
            #pragma unroll
            for (int j = 0; j < 4; ++j) {
                float xk = (j == 0) ? xv.x : (j == 1) ? xv.y : (j == 2) ? xv.z : xv.w;
                const float4* wr = w4 + (k4 * 4 + j) * 4;   // uniform across wave
                float4 w0 = wr[0], w1v = wr[1], w2v = wr[2], w3v = wr[3];
                a0.x += xk * w0.x;  a0.y += xk * w0.y;  a0.z += xk * w0.z;  a0.w += xk * w0.w;
                a1.x += xk * w1v.x; a1.y += xk * w1v.y; a1.z += xk * w1v.z; a1.w += xk * w1v.w;
                a2.x += xk * w2v.x; a2.y += xk * w2v.y; a2.z += xk * w2v.z; a2.w += xk * w2v.w;
                a3.x += xk * w3v.x; a3.y += xk * w3v.y; a3.z += xk * w3v.z; a3.w += xk * w3v.w;
            }
        }
        float4* hr = (float4*)(h1 + row * D_H);
        hr[0] = a0; hr[1] = a1; hr[2] = a2; hr[3] = a3;
    } else {
        // ---- two-phase bucket scatter, dst read once (reg-cached packs) ----
        int base_e = (bid - G_BLKS) * SC_CH;
        int ni4 = min((N_EDGES - base_e) >> 2, SC_I4);
        for (int b = tid; b < K_BUCK; b += 256) hist[b] = 0;
        __syncthreads();
        const int4* d4p = (const int4*)(dst + base_e);
        const int4* s4p = (const int4*)(src + base_e);
        int4 pk0, pk1, pk2;
        bool a0 = tid < ni4, a1 = tid + 256 < ni4, a2 = tid + 512 < ni4;
        if (a0) { int4 d = d4p[tid];       PACKH(pk0, d); }
        if (a1) { int4 d = d4p[tid + 256]; PACKH(pk1, d); }
        if (a2) { int4 d = d4p[tid + 512]; PACKH(pk2, d); }
        __syncthreads();
        if (tid < K_BUCK)
            cur[tid] = (tid << BSHIFT) + atomicAdd(&gcur[tid * GC_PAD], hist[tid]);
        __syncthreads();
        if (a0) { int4 sv = s4p[tid];       SCAT(pk0, sv); }
        if (a1) { int4 sv = s4p[tid + 256]; SCAT(pk1, sv); }
        if (a2) { int4 sv = s4p[tid + 512]; SCAT(pk2, sv); }
    }
}

// ---- K2: per-bucket counting sort -> CSR (single arr read via LDS staging);
//      dinv; scale h1 *= dinv in place. 256 blocks x 512 threads. ----
__global__ __launch_bounds__(512) void k2_build_csr(
        const int* __restrict__ arr, const int* __restrict__ gcur,
        float* __restrict__ h1, float* __restrict__ dinv,
        int* __restrict__ csr, int2* __restrict__ meta) {
    __shared__ int sarr[BCAP];          // 16 KB: bucket entries staged once
    __shared__ int cnt[NPB2];
    __shared__ int pref[NPB2];
    __shared__ int cur[NPB2];
    __shared__ float sdi[NPB2];
    int k = blockIdx.x, tid = threadIdx.x;
    for (int i = tid; i < NPB2; i += 512) cnt[i] = 0;
    __syncthreads();
    int count = min(gcur[k * GC_PAD], BCAP);
    int base = k << BSHIFT;
    // stage + histogram in one pass (the only global read of arr)
    for (int i = tid; i < count; i += 512) {
        int v = arr[base + i];
        sarr[i] = v;
        atomicAdd(&cnt[v & 255], 1);
    }
    __syncthreads();
    if (tid == 0) {
        int run = 0;
        for (int l = 0; l < NPB2; ++l) { pref[l] = run; run += cnt[l]; }
    }
    __syncthreads();
    int n0 = k * NPB2;
    int ncnt = min(NPB2, N_NODES - n0);
    for (int l = tid; l < ncnt; l += 512) {
        cur[l] = pref[l];
        meta[n0 + l] = make_int2(base + pref[l], cnt[l]);
        float di = rsqrtf((float)cnt[l] + 1.0f);   // +1 = self loop
        sdi[l] = di;
        dinv[n0 + l] = di;
    }
    __syncthreads();
    // scale h1 in place: h1s[n][:] = h1[n][:] * dinv[n]
    for (int g = tid; g < ncnt * 4; g += 512) {
        int l = g >> 2;
        float di = sdi[l];
        float4* p = (float4*)(h1 + (n0 + l) * D_H);
        float4 v = p[g & 3];
        v.x *= di; v.y *= di; v.z *= di; v.w *= di;
        p[g & 3] = v;
    }
    // scatter to csr from LDS (grouped by local dst)
    for (int i = tid; i < count; i += 512) {
        int p = sarr[i];
        int l = p & 255;
        int pos = atomicAdd(&cur[l], 1);
        csr[base + pos] = p >> 8;
    }
}

// ---- K3: encoder agg, 4 lanes/node, register accumulate.
//      zs[n][:] = di*( di*(h1s_self + S h1s[src]) + b1 )   (pre-scaled z) ----
__global__ __launch_bounds__(256) void k3_agg_enc(
        const float4* __restrict__ h1s4, const int* __restrict__ csr,
        const int2* __restrict__ meta, const float* __restrict__ dinv,
        const float* __restrict__ b1, float4* __restrict__ zs4) {
    int tid = threadIdx.x;
    int q = tid & 3;
    int n = blockIdx.x * 64 + (tid >> 2);
    if (n >= N_NODES) return;
    int qb = tid & 60;                 // quad base lane within wave
    int2 m = meta[n];                  // same addr across quad -> broadcast
    int e = m.x, end = m.x + m.y;
    float4 acc = {0.0f, 0.0f, 0.0f, 0.0f};
    for (; e < end; e += 4) {
        int myidx = 0;
        if (e + q < end) myidx = csr[e + q];   // coalesced 16B per quad
        #pragma unroll
        for (int j = 0; j < 4; ++j) {
            int idx = __shfl(myidx, qb + j, 64);
            if (e + j < end) {
                float4 v = h1s4[idx * 4 + q];  // quad covers one 64B line
                acc.x += v.x; acc.y += v.y; acc.z += v.z; acc.w += v.w;
            }
        }
    }
    float di = dinv[n];
    float4 hv = h1s4[n * 4 + q];       // self (already *dinv)
    float4 bv = ((const float4*)b1)[q];
    float4 z;
    z.x = di * (di * (acc.x + hv.x) + bv.x);
    z.y = di * (di * (acc.y + hv.y) + bv.y);
    z.z = di * (di * (acc.z + hv.z) + bv.z);
    z.w = di * (di * (acc.w + hv.w) + bv.w);
    zs4[n * 4 + q] = z;
}

// ---- K4: decoder agg (CSR quad) + W2 GEMM epilogue with uniform broadcasts ----
__global__ __launch_bounds__(512) void k4_agg_dec_out(
        const float4* __restrict__ zs4, const int* __restrict__ csr,
        const int2* __restrict__ meta, const float* __restrict__ dinv,
        const float* __restrict__ W2, const float* __restrict__ b2,
        float* __restrict__ out) {
    __shared__ float agL[K4_NPB * 17];                // 8.7 KB (pad 17: bank-clean)
    __shared__ __align__(16) float w2s[D_H * D_IN];   // 8 KB
    int tid = threadIdx.x;
    for (int i = tid; i < D_H * D_IN; i += 512) w2s[i] = W2[i];
    int q = tid & 3;
    int nloc = tid >> 2;               // 0..127
    int n0 = blockIdx.x * K4_NPB;
    int n = n0 + nloc;
    int qb = tid & 60;
    if (n < N_NODES) {
        int2 m = meta[n];
        int e = m.x, end = m.x + m.y;
        float4 acc = {0.0f, 0.0f, 0.0f, 0.0f};
        for (; e < end; e += 4) {
            int myidx = 0;
            if (e + q < end) myidx = csr[e + q];
            #pragma unroll
            for (int j = 0; j < 4; ++j) {
                int idx = __shfl(myidx, qb + j, 64);
                if (e + j < end) {
                    float4 v = zs4[idx * 4 + q];
                    acc.x += v.x; acc.y += v.y; acc.z += v.z; acc.w += v.w;
                }
            }
        }
        float di = dinv[n];
        float4 zv = zs4[n * 4 + q];    // self (zs pre-scaled)
        agL[nloc * 17 + q * 4 + 0] = di * (acc.x + zv.x);
        agL[nloc * 17 + q * 4 + 1] = di * (acc.y + zv.y);
        agL[nloc * 17 + q * 4 + 2] = di * (acc.z + zv.z);
        agL[nloc * 17 + q * 4 + 3] = di * (acc.w + zv.w);
    }
    __syncthreads();
    // epilogue: thread = (quarter = tid>>7 [wave-aligned], ne = tid&127)
    // w2s reads are same-address broadcasts across the wave (quarter uniform).
    int quarter = tid >> 7;
    int ne = tid & 127;
    if (n0 + ne < N_NODES) {
        const float* arow = &agL[ne * 17];
        float4 o[8];
        const float4* b2q = (const float4*)(b2 + quarter * 32);
        #pragma unroll
        for (int u = 0; u < 8; ++u) o[u] = b2q[u];
        #pragma unroll
        for (int c = 0; c < D_H; ++c) {
            float ac = arow[c];
            const float4* wr = (const float4*)(w2s + c * D_IN + quarter * 32);
            #pragma unroll
            for (int u = 0; u < 8; ++u) {
                float4 w = wr[u];
                o[u].x += ac * w.x; o[u].y += ac * w.y;
                o[u].z += ac * w.z; o[u].w += ac * w.w;
            }
        }
        float4* orow = (float4*)(out + (n0 + ne) * D_IN + quarter * 32);
        #pragma unroll
        for (int u = 0; u < 8; ++u) orow[u] = o[u];
    }
}

extern "C" void kernel_launch(void* const* d_in, const int* in_sizes, int n_in,
                              void* d_out, int out_size, void* d_ws, size_t ws_size,
                              hipStream_t stream) {
    const float* x  = (const float*)d_in[0];
    const int*   ei = (const int*)d_in[1];   // [2, E]: src then dst
    const float* W1 = (const float*)d_in[2];
    const float* b1 = (const float*)d_in[3];
    const float* W2 = (const float*)d_in[4];
    const float* b2 = (const float*)d_in[5];
    float* out = (float*)d_out;

    const int* src = ei;
    const int* dst = ei + N_EDGES;

    // ws carve: gcur | dinv[N] | h1[N*16] | zs[N*16] | meta[N int2]
    //           | arr[256*4096] | csr[256*4096]   (~15.2 MB)
    char* base = (char*)d_ws;
    int*    gcur = (int*)base;                 base += K_BUCK * GC_PAD * 4;
    float*  dinv = (float*)base;               base += N_NODES * 4;
    float*  h1   = (float*)base;               base += N_NODES * D_H * 4;
    float*  zs   = (float*)base;               base += N_NODES * D_H * 4;
    int2*   meta = (int2*)base;                base += N_NODES * 8;
    int*    arr  = (int*)base;                 base += K_BUCK * BCAP * 4;
    int*    csr  = (int*)base;                 base += K_BUCK * BCAP * 4;

    hipMemsetAsync(gcur, 0, K_BUCK * GC_PAD * sizeof(int), stream);

    k1_fused<<<G_BLKS + SC_BLKS, 256, 0, stream>>>(src, dst, x, W1, gcur, h1, arr);
    k2_build_csr<<<K_BUCK, 512, 0, stream>>>(arr, gcur, h1, dinv, csr, meta);
    k3_agg_enc<<<(N_NODES + 63) / 64, 256, 0, stream>>>((const float4*)h1, csr, meta, dinv, b1, (float4*)zs);
    k4_agg_dec_out<<<(N_NODES + K4_NPB - 1) / K4_NPB, 512, 0, stream>>>((const float4*)zs, csr, meta, dinv, W2, b2, out);
}